// Round 7
// baseline (153.005 us; speedup 1.0000x reference)
//
#include <hip/hip_runtime.h>
#include <hip/hip_bf16.h>

// Problem constants
#define BATCH 16384
#define GATES 1023
#define NPAD  1024
#define OUTF  128

typedef unsigned short ushortT;
typedef short bf16x8 __attribute__((ext_vector_type(8)));
typedef float f32x4 __attribute__((ext_vector_type(4)));

__device__ inline float bf2f(ushortT u) {
    union { unsigned int i; float f; } v;
    v.i = ((unsigned int)u) << 16;
    return v.f;
}
__device__ inline ushortT f2bf(float f) {
    union { float f; unsigned int i; } v;
    v.f = f;
    unsigned int x = v.i;
    unsigned int r = (x + 0x7FFFu + ((x >> 16) & 1u)) >> 16;  // RNE
    return (ushortT)r;
}

// async global->LDS, 16B/lane; lds base wave-uniform, HW writes base + lane*16.
__device__ inline void gl2lds16(const void* gptr, void* ldsptr) {
    __builtin_amdgcn_global_load_lds(
        (const __attribute__((address_space(1))) void*)gptr,
        (__attribute__((address_space(3))) void*)ldsptr, 16, 0, 0);
}

// ---------------- prep (R6, coalesced LDS-bounce transpose) ----------------
__global__ void k_prep(const float* __restrict__ gw, const float* __restrict__ gb,
                       const float* __restrict__ z, ushortT* __restrict__ gwT,
                       float* __restrict__ gbp, ushortT* __restrict__ zh) {
    const int b = blockIdx.x, t = threadIdx.x;
    if (b < 64) {
        __shared__ ushortT sT[256 * 17];
        const int nb = b * 16, nloc = t & 15, kb = t >> 4;
#pragma unroll
        for (int kk = 0; kk < 16; ++kk) {
            int k = kk * 16 + kb;
            int n = nb + nloc;
            float v = (n < GATES) ? gw[(size_t)k * GATES + n] : 0.f;
            sT[k * 17 + nloc] = f2bf(v);
        }
        __syncthreads();
#pragma unroll
        for (int nn = 0; nn < 16; ++nn)
            gwT[(size_t)(nb + nn) * 256 + t] = sT[t * 17 + nn];
    } else if (b < 128) {
        int i = (b - 64) * 256 + t;
        const float4* p = (const float4*)z + (size_t)i * 2;
        float4 a = p[0], c = p[1];
        ushortT o[8] = {f2bf(a.x), f2bf(a.y), f2bf(a.z), f2bf(a.w),
                        f2bf(c.x), f2bf(c.y), f2bf(c.z), f2bf(c.w)};
        *(bf16x8*)(zh + (size_t)i * 8) = *(bf16x8*)o;
    } else {
#pragma unroll
        for (int u = 0; u < 4; ++u) {
            int i = t * 4 + u;
            gbp[i] = (i < GATES) ? gb[i] : 0.f;
        }
    }
}

// ---------------- GEMM1, K-in-registers: gat = sigmoid(x @ gw + gb) --------
// BM=64, BN=128, K=256 entirely in VGPRs (af: 16 x bf16x8 = 64 VGPR).
// K-loop stages ONLY B (gwT slice, 8 KB/iter, m97 2-barrier pattern).
// 8 MFMA : 4 ds_read per iter; LDS 8 KB -> 3 blocks/CU (12 waves/CU).
__global__ __launch_bounds__(256, 3) void gemm1_regA(const float* __restrict__ x,
                                                     const ushortT* __restrict__ gwT,
                                                     const float* __restrict__ gbp,
                                                     ushortT* __restrict__ gat) {
    __shared__ ushortT sB[128 * 32];  // 8 KB

    const int tid = threadIdx.x;
    const int wave = tid >> 6, lane = tid & 63;
    const int quad = lane >> 4, l15 = lane & 15;
    const int wr = wave >> 1, wc = wave & 1;  // 2x2 waves; wave tile 32x64
    const int bm = blockIdx.y * 64, bn = blockIdx.x * 128;
    const int lrow = lane >> 2, lcol = (lane & 3) * 8;

    // A-panel (x, f32) -> bf16 fragments in registers: af[mt][c] = rows
    // bm + wr*32 + mt*16 + l15, k = c*32 + quad*8 .. +7   (R3/R6-verified map)
    bf16x8 af[2][8];
#pragma unroll
    for (int mt = 0; mt < 2; ++mt) {
        const float* xr = x + (size_t)(bm + wr * 32 + mt * 16 + l15) * 256 + quad * 8;
#pragma unroll
        for (int c = 0; c < 8; ++c) {
            float4 a = *(const float4*)(xr + c * 32);
            float4 b = *(const float4*)(xr + c * 32 + 4);
            ushortT o[8] = {f2bf(a.x), f2bf(a.y), f2bf(a.z), f2bf(a.w),
                            f2bf(b.x), f2bf(b.y), f2bf(b.z), f2bf(b.w)};
            af[mt][c] = *(bf16x8*)o;
        }
    }
    float bias[4];
#pragma unroll
    for (int j = 0; j < 4; ++j)
        bias[j] = gbp[bn + wc * 64 + j * 16 + l15];

    f32x4 acc[2][4] = {};
    const ushortT* Bbase = gwT + (size_t)bn * 256;

    for (int k0 = 0; k0 < 256; k0 += 32) {
        // stage B rows [bn, bn+128) x k [k0, k0+32) -> sB (m97 layout [row][32])
#pragma unroll
        for (int r = 0; r < 2; ++r) {
            int e = wave * 2 + r;
            gl2lds16(Bbase + (size_t)(e * 16 + lrow) * 256 + k0 + lcol, sB + e * 512);
        }
        __syncthreads();
        const int c = k0 >> 5;
#pragma unroll
        for (int j = 0; j < 4; ++j) {
            bf16x8 bfr = *(const bf16x8*)(sB + (wc * 64 + j * 16 + l15) * 32 + quad * 8);
            acc[0][j] = __builtin_amdgcn_mfma_f32_16x16x32_bf16(af[0][c], bfr, acc[0][j], 0, 0, 0);
            acc[1][j] = __builtin_amdgcn_mfma_f32_16x16x32_bf16(af[1][c], bfr, acc[1][j], 0, 0, 0);
        }
        __syncthreads();
    }

    // epilogue: C/D row = quad*4 + reg, col = l15 (m89-verified); sigmoid + bf16
#pragma unroll
    for (int mt = 0; mt < 2; ++mt) {
        int gm = bm + wr * 32 + mt * 16 + quad * 4;
#pragma unroll
        for (int j = 0; j < 4; ++j) {
            int gn = bn + wc * 64 + j * 16 + l15;
            float bv = bias[j];
#pragma unroll
            for (int r = 0; r < 4; ++r) {
                float g = 1.f / (1.f + __expf(-(acc[mt][j][r] + bv)));
                gat[(size_t)(gm + r) * NPAD + gn] = f2bf(g);
            }
        }
    }
}

// ---------------- tree (R1 verbatim, BW-floor): gat -> leaf ----------------
__global__ __launch_bounds__(256) void k_tree(const ushortT* __restrict__ gat,
                                              ushortT* __restrict__ leaf) {
    const int wave = threadIdx.x >> 6, lane = threadIdx.x & 63;
    const int row = blockIdx.x * 4 + wave;
    const ushortT* gr = gat + (size_t)row * NPAD;

    float P = 1.f;
#pragma unroll
    for (int d = 0; d < 6; ++d) {
        int idx = (1 << d) - 1 + (lane >> (6 - d));
        float g = bf2f(gr[idx]);
        int bit = (lane >> (5 - d)) & 1;
        P *= bit ? (1.f - g) : g;
    }
    float v[16];
    v[0] = P;
#pragma unroll
    for (int d = 0; d < 4; ++d) {
        const int cnt = 1 << d;
        const int base = (1 << (d + 6)) - 1 + (lane << d);
#pragma unroll
        for (int t = 7; t >= 0; --t) {
            if (t < cnt) {
                float g = bf2f(gr[base + t]);
                float pv = v[t];
                float a = pv * g;
                v[2 * t] = a;
                v[2 * t + 1] = pv - a;
            }
        }
    }
    ushortT o[16];
#pragma unroll
    for (int t = 0; t < 16; ++t) o[t] = f2bf(v[t]);
    ushortT* dst = leaf + (size_t)row * NPAD + lane * 16;
    *(bf16x8*)(dst) = *(bf16x8*)o;
    *(bf16x8*)(dst + 8) = *(bf16x8*)(o + 8);
}

// ---------------- GEMM2 (R1-proven template): out = leaf @ z^T -------------
template <int BM, int BN, int K, int LDA, int LDB, int LDC>
__global__ __launch_bounds__(256) void gemm_bt(const ushortT* __restrict__ A,
                                               const ushortT* __restrict__ B,
                                               float* __restrict__ C) {
    constexpr int MT = BM / 32, NT = BN / 32;
    constexpr int RA = BM / 64, RB = BN / 64;
    __shared__ ushortT sA[BM * 32];
    __shared__ ushortT sB[BN * 32];

    const int tid = threadIdx.x;
    const int wave = tid >> 6, lane = tid & 63;
    const int quad = lane >> 4, l15 = lane & 15;
    const int wr = wave >> 1, wc = wave & 1;
    const int m_wave = wr * (BM / 2), n_wave = wc * (BN / 2);
    const int bm = blockIdx.y * BM, bn = blockIdx.x * BN;
    const int r_in = lane >> 2, c_in = (lane & 3) * 8;

    f32x4 acc[MT][NT] = {};
    const ushortT* Abase = A + (size_t)bm * LDA;
    const ushortT* Bbase = B + (size_t)bn * LDB;

    for (int k0 = 0; k0 < K; k0 += 32) {
#pragma unroll
        for (int r = 0; r < RA; ++r) {
            int e = wave * RA + r;
            gl2lds16(Abase + (size_t)(e * 16 + r_in) * LDA + k0 + c_in, sA + e * 512);
        }
#pragma unroll
        for (int r = 0; r < RB; ++r) {
            int e = wave * RB + r;
            gl2lds16(Bbase + (size_t)(e * 16 + r_in) * LDB + k0 + c_in, sB + e * 512);
        }
        __syncthreads();

        bf16x8 afr[MT], bfr[NT];
#pragma unroll
        for (int i = 0; i < MT; ++i)
            afr[i] = *(const bf16x8*)(sA + (m_wave + i * 16 + l15) * 32 + quad * 8);
#pragma unroll
        for (int j = 0; j < NT; ++j)
            bfr[j] = *(const bf16x8*)(sB + (n_wave + j * 16 + l15) * 32 + quad * 8);
#pragma unroll
        for (int i = 0; i < MT; ++i)
#pragma unroll
            for (int j = 0; j < NT; ++j)
                acc[i][j] = __builtin_amdgcn_mfma_f32_16x16x32_bf16(afr[i], bfr[j],
                                                                    acc[i][j], 0, 0, 0);
        __syncthreads();
    }

#pragma unroll
    for (int i = 0; i < MT; ++i) {
        int gm = bm + m_wave + i * 16 + quad * 4;
#pragma unroll
        for (int j = 0; j < NT; ++j) {
            int gn = bn + n_wave + j * 16 + l15;
#pragma unroll
            for (int r = 0; r < 4; ++r)
                C[(size_t)(gm + r) * LDC + gn] = acc[i][j][r];
        }
    }
}

// ---------------- launch ----------------
extern "C" void kernel_launch(void* const* d_in, const int* in_sizes, int n_in,
                              void* d_out, int out_size, void* d_ws, size_t ws_size,
                              hipStream_t stream) {
    const float* x  = (const float*)d_in[0];   // 16384 x 256
    const float* gw = (const float*)d_in[1];   // 256 x 1023
    const float* gb = (const float*)d_in[2];   // 1023
    const float* z  = (const float*)d_in[3];   // 128 x 1024
    float* out = (float*)d_out;                // 16384 x 128

    char* ws = (char*)d_ws;
    ushortT* gwT  = (ushortT*)(ws + 0);         //    524,288 B
    ushortT* zh   = (ushortT*)(ws + 524288);    //    262,144 B
    float*   gbp  = (float*)  (ws + 786432);    //      4,096 B
    ushortT* gat  = (ushortT*)(ws + 790528);    // 33,554,432 B
    ushortT* leaf = (ushortT*)(ws + 34344960);  // 33,554,432 B (total ~67.9 MB)

    k_prep<<<129, 256, 0, stream>>>(gw, gb, z, gwT, gbp, zh);

    // GEMM1: M=16384 N=1024 K=256, A-panel in registers, 2048 blocks
    gemm1_regA<<<dim3(8, 256), 256, 0, stream>>>(x, gwT, gbp, gat);

    // tree: leaf densities, 1 wave/row
    k_tree<<<4096, 256, 0, stream>>>(gat, leaf);

    // GEMM2: M=16384 N=128 K=1024, leaf read once (BN=128), 256 blocks
    gemm_bt<64, 128, 1024, 1024, 1024, 128>
        <<<dim3(1, 256), 256, 0, stream>>>(leaf, zh, out);
}

// Round 8
// 133.658 us; speedup vs baseline: 1.1448x; 1.1448x over previous
//
#include <hip/hip_runtime.h>
#include <hip/hip_bf16.h>

// Problem constants
#define BATCH 16384
#define GATES 1023
#define NPAD  1024
#define OUTF  128

typedef unsigned short ushortT;
typedef short bf16x8 __attribute__((ext_vector_type(8)));
typedef float f32x4 __attribute__((ext_vector_type(4)));

__device__ inline float bf2f(ushortT u) {
    union { unsigned int i; float f; } v;
    v.i = ((unsigned int)u) << 16;
    return v.f;
}
__device__ inline ushortT f2bf(float f) {
    union { float f; unsigned int i; } v;
    v.f = f;
    unsigned int x = v.i;
    unsigned int r = (x + 0x7FFFu + ((x >> 16) & 1u)) >> 16;  // RNE
    return (ushortT)r;
}

// async global->LDS, 16B/lane; lds base wave-uniform, HW writes base + lane*16.
__device__ inline void gl2lds16(const void* gptr, void* ldsptr) {
    __builtin_amdgcn_global_load_lds(
        (const __attribute__((address_space(1))) void*)gptr,
        (__attribute__((address_space(3))) void*)ldsptr, 16, 0, 0);
}

// ---------------- prep: transpose gw, pad gb, convert z and x --------------
// blocks [0,64):      gw (256x1023 f32) -> gwT (1024x256 bf16), LDS-bounce
// blocks [64,128):    z -> zh bf16
// block  128:         gb -> gbp padded
// blocks [129,2177):  x -> xh bf16 (8 elems/thread)
__global__ void k_prep(const float* __restrict__ gw, const float* __restrict__ gb,
                       const float* __restrict__ z, const float* __restrict__ x,
                       ushortT* __restrict__ gwT, float* __restrict__ gbp,
                       ushortT* __restrict__ zh, ushortT* __restrict__ xh) {
    const int b = blockIdx.x, t = threadIdx.x;
    if (b < 64) {
        __shared__ ushortT sT[256 * 17];
        const int nb = b * 16, nloc = t & 15, kb = t >> 4;
#pragma unroll
        for (int kk = 0; kk < 16; ++kk) {
            int k = kk * 16 + kb;
            int n = nb + nloc;
            float v = (n < GATES) ? gw[(size_t)k * GATES + n] : 0.f;
            sT[k * 17 + nloc] = f2bf(v);
        }
        __syncthreads();
#pragma unroll
        for (int nn = 0; nn < 16; ++nn)
            gwT[(size_t)(nb + nn) * 256 + t] = sT[t * 17 + nn];
    } else if (b < 128) {
        int i = (b - 64) * 256 + t;
        const float4* p = (const float4*)z + (size_t)i * 2;
        float4 a = p[0], c = p[1];
        ushortT o[8] = {f2bf(a.x), f2bf(a.y), f2bf(a.z), f2bf(a.w),
                        f2bf(c.x), f2bf(c.y), f2bf(c.z), f2bf(c.w)};
        *(bf16x8*)(zh + (size_t)i * 8) = *(bf16x8*)o;
    } else if (b == 128) {
#pragma unroll
        for (int u = 0; u < 4; ++u) {
            int i = t * 4 + u;
            gbp[i] = (i < GATES) ? gb[i] : 0.f;
        }
    } else {
        int i = (b - 129) * 256 + t;  // 524288 groups of 8
        const float4* p = (const float4*)x + (size_t)i * 2;
        float4 a = p[0], c = p[1];
        ushortT o[8] = {f2bf(a.x), f2bf(a.y), f2bf(a.z), f2bf(a.w),
                        f2bf(c.x), f2bf(c.y), f2bf(c.z), f2bf(c.w)};
        *(bf16x8*)(xh + (size_t)i * 8) = *(bf16x8*)o;
    }
}

// ---------------- GEMM1 (R1-proven m97 128x128): gat = sigmoid(xh@gwT^T + gb) ----
// 16 MFMA : 8 ds_read_b128 per wave-iter; N-major grid => the 8 blocks sharing an
// M-tile dispatch adjacently (one per XCD), xh tile L3-resident across XCDs.
__global__ __launch_bounds__(256) void gemm1_sig(const ushortT* __restrict__ A,
                                                 const ushortT* __restrict__ B,
                                                 const float* __restrict__ bias,
                                                 ushortT* __restrict__ C) {
    __shared__ ushortT sA[128 * 32];
    __shared__ ushortT sB[128 * 32];

    const int tid = threadIdx.x;
    const int wave = tid >> 6, lane = tid & 63;
    const int quad = lane >> 4, l15 = lane & 15;
    const int wr = wave >> 1, wc = wave & 1;
    const int m_wave = wr * 64, n_wave = wc * 64;
    const int bm = blockIdx.y * 128, bn = blockIdx.x * 128;
    const int r_in = lane >> 2, c_in = (lane & 3) * 8;

    f32x4 acc[4][4] = {};
    const ushortT* Abase = A + (size_t)bm * 256;
    const ushortT* Bbase = B + (size_t)bn * 256;

    for (int k0 = 0; k0 < 256; k0 += 32) {
#pragma unroll
        for (int r = 0; r < 2; ++r) {
            int e = wave * 2 + r;
            gl2lds16(Abase + (size_t)(e * 16 + r_in) * 256 + k0 + c_in, sA + e * 512);
            gl2lds16(Bbase + (size_t)(e * 16 + r_in) * 256 + k0 + c_in, sB + e * 512);
        }
        __syncthreads();

        bf16x8 afr[4], bfr[4];
#pragma unroll
        for (int i = 0; i < 4; ++i)
            afr[i] = *(const bf16x8*)(sA + (m_wave + i * 16 + l15) * 32 + quad * 8);
#pragma unroll
        for (int j = 0; j < 4; ++j)
            bfr[j] = *(const bf16x8*)(sB + (n_wave + j * 16 + l15) * 32 + quad * 8);
#pragma unroll
        for (int i = 0; i < 4; ++i)
#pragma unroll
            for (int j = 0; j < 4; ++j)
                acc[i][j] = __builtin_amdgcn_mfma_f32_16x16x32_bf16(afr[i], bfr[j],
                                                                    acc[i][j], 0, 0, 0);
        __syncthreads();
    }

    // C/D: row = quad*4 + reg, col = l15 (m89-verified); sigmoid + bf16 store
#pragma unroll
    for (int i = 0; i < 4; ++i) {
        int gm = bm + m_wave + i * 16 + quad * 4;
#pragma unroll
        for (int j = 0; j < 4; ++j) {
            int gn = bn + n_wave + j * 16 + l15;
            float bv = bias[gn];
#pragma unroll
            for (int r = 0; r < 4; ++r) {
                float g = 1.f / (1.f + __expf(-(acc[i][j][r] + bv)));
                C[(size_t)(gm + r) * NPAD + gn] = f2bf(g);
            }
        }
    }
}

// ---------------- tree (R1 verbatim, BW-floor): gat -> leaf ----------------
__global__ __launch_bounds__(256) void k_tree(const ushortT* __restrict__ gat,
                                              ushortT* __restrict__ leaf) {
    const int wave = threadIdx.x >> 6, lane = threadIdx.x & 63;
    const int row = blockIdx.x * 4 + wave;
    const ushortT* gr = gat + (size_t)row * NPAD;

    float P = 1.f;
#pragma unroll
    for (int d = 0; d < 6; ++d) {
        int idx = (1 << d) - 1 + (lane >> (6 - d));
        float g = bf2f(gr[idx]);
        int bit = (lane >> (5 - d)) & 1;
        P *= bit ? (1.f - g) : g;
    }
    float v[16];
    v[0] = P;
#pragma unroll
    for (int d = 0; d < 4; ++d) {
        const int cnt = 1 << d;
        const int base = (1 << (d + 6)) - 1 + (lane << d);
#pragma unroll
        for (int t = 7; t >= 0; --t) {
            if (t < cnt) {
                float g = bf2f(gr[base + t]);
                float pv = v[t];
                float a = pv * g;
                v[2 * t] = a;
                v[2 * t + 1] = pv - a;
            }
        }
    }
    ushortT o[16];
#pragma unroll
    for (int t = 0; t < 16; ++t) o[t] = f2bf(v[t]);
    ushortT* dst = leaf + (size_t)row * NPAD + lane * 16;
    *(bf16x8*)(dst) = *(bf16x8*)o;
    *(bf16x8*)(dst + 8) = *(bf16x8*)(o + 8);
}

// ---------------- GEMM2: out = leaf @ z^T, BM=64 BN=128 (leaf read once) ---
__global__ __launch_bounds__(256) void gemm2(const ushortT* __restrict__ A,
                                             const ushortT* __restrict__ B,
                                             float* __restrict__ C) {
    __shared__ ushortT sA[64 * 32];   // 4 KB
    __shared__ ushortT sB[128 * 32];  // 8 KB

    const int tid = threadIdx.x;
    const int wave = tid >> 6, lane = tid & 63;
    const int quad = lane >> 4, l15 = lane & 15;
    const int wr = wave >> 1, wc = wave & 1;
    const int m_wave = wr * 32, n_wave = wc * 64;
    const int bm = blockIdx.x * 64;
    const int r_in = lane >> 2, c_in = (lane & 3) * 8;

    f32x4 acc[2][4] = {};
    const ushortT* Abase = A + (size_t)bm * NPAD;

    for (int k0 = 0; k0 < 1024; k0 += 32) {
        {
            int e = wave;  // 4 waves cover 64 A rows
            gl2lds16(Abase + (size_t)(e * 16 + r_in) * NPAD + k0 + c_in, sA + e * 512);
#pragma unroll
            for (int r = 0; r < 2; ++r) {
                int eb = wave * 2 + r;
                gl2lds16(B + (size_t)(eb * 16 + r_in) * NPAD + k0 + c_in, sB + eb * 512);
            }
        }
        __syncthreads();

        bf16x8 afr[2], bfr[4];
#pragma unroll
        for (int i = 0; i < 2; ++i)
            afr[i] = *(const bf16x8*)(sA + (m_wave + i * 16 + l15) * 32 + quad * 8);
#pragma unroll
        for (int j = 0; j < 4; ++j)
            bfr[j] = *(const bf16x8*)(sB + (n_wave + j * 16 + l15) * 32 + quad * 8);
#pragma unroll
        for (int i = 0; i < 2; ++i)
#pragma unroll
            for (int j = 0; j < 4; ++j)
                acc[i][j] = __builtin_amdgcn_mfma_f32_16x16x32_bf16(afr[i], bfr[j],
                                                                    acc[i][j], 0, 0, 0);
        __syncthreads();
    }

#pragma unroll
    for (int i = 0; i < 2; ++i) {
        int gm = bm + m_wave + i * 16 + quad * 4;
#pragma unroll
        for (int j = 0; j < 4; ++j) {
            int gn = n_wave + j * 16 + l15;
#pragma unroll
            for (int r = 0; r < 4; ++r)
                C[(size_t)(gm + r) * OUTF + gn] = acc[i][j][r];
        }
    }
}

// ---------------- launch ----------------
extern "C" void kernel_launch(void* const* d_in, const int* in_sizes, int n_in,
                              void* d_out, int out_size, void* d_ws, size_t ws_size,
                              hipStream_t stream) {
    const float* x  = (const float*)d_in[0];   // 16384 x 256
    const float* gw = (const float*)d_in[1];   // 256 x 1023
    const float* gb = (const float*)d_in[2];   // 1023
    const float* z  = (const float*)d_in[3];   // 128 x 1024
    float* out = (float*)d_out;                // 16384 x 128

    char* ws = (char*)d_ws;
    ushortT* gwT  = (ushortT*)(ws + 0);         //    524,288 B
    ushortT* zh   = (ushortT*)(ws + 524288);    //    262,144 B
    float*   gbp  = (float*)  (ws + 786432);    //      4,096 B
    ushortT* xh   = (ushortT*)(ws + 790528);    //  8,388,608 B
    ushortT* gat  = (ushortT*)(ws + 9179136);   // 33,554,432 B
    ushortT* leaf = (ushortT*)(ws + 42733568);  // 33,554,432 B (~76 MB)

    k_prep<<<2177, 256, 0, stream>>>(gw, gb, z, x, gwT, gbp, zh, xh);

    // GEMM1: M=16384 N=1024 K=256 (N-major grid for XCD-shared xh tiles)
    gemm1_sig<<<dim3(8, 128), 256, 0, stream>>>(xh, gwT, gbp, gat);

    // tree: 1 wave/row
    k_tree<<<4096, 256, 0, stream>>>(gat, leaf);

    // GEMM2: M=16384 N=128 K=1024, leaf read once
    gemm2<<<256, 256, 0, stream>>>(leaf, zh, out);
}